// Round 1
// baseline (629.286 us; speedup 1.0000x reference)
//
#include <hip/hip_runtime.h>

// VQ: N=262144 rows, DIM=64, K=1024 codes.
// score(c) = ||e_c||^2 - 2 x.e_c  (||x||^2 dropped: constant per row)
// argmin with first-min-wins (strict <, ascending c) == np.argmin.

#define VQ_N 262144
#define VQ_DIM 64
#define VQ_K 1024
#define VQ_BLOCK 256

__global__ __launch_bounds__(VQ_BLOCK, 4)
void vq_fp32_kernel(const float* __restrict__ x,
                    const float* __restrict__ embed,
                    float* __restrict__ out) {
    __shared__ float e2s[VQ_K];
    const int tid = threadIdx.x;

    // Cooperative ||e_c||^2 into LDS (each block recomputes; 256 MAC/thread, trivial).
    for (int c = tid; c < VQ_K; c += VQ_BLOCK) {
        const float4* ep = reinterpret_cast<const float4*>(embed + c * VQ_DIM);
        float s = 0.0f;
#pragma unroll
        for (int j = 0; j < VQ_DIM / 4; ++j) {
            float4 v = ep[j];
            s = fmaf(v.x, v.x, s);
            s = fmaf(v.y, v.y, s);
            s = fmaf(v.z, v.z, s);
            s = fmaf(v.w, v.w, s);
        }
        e2s[c] = s;
    }
    __syncthreads();

    const int row = blockIdx.x * VQ_BLOCK + tid;

    // x row -> 64 VGPRs
    float xr[VQ_DIM];
    {
        const float4* xp = reinterpret_cast<const float4*>(x + (size_t)row * VQ_DIM);
#pragma unroll
        for (int j = 0; j < VQ_DIM / 4; ++j) {
            float4 v = xp[j];
            xr[4 * j + 0] = v.x;
            xr[4 * j + 1] = v.y;
            xr[4 * j + 2] = v.z;
            xr[4 * j + 3] = v.w;
        }
    }

    float best = __builtin_inff();
    int bidx = 0;

    // Main loop: codes are wave-uniform -> embed reads should scalarize to s_load.
    for (int c = 0; c < VQ_K; ++c) {
        const float4* ep = reinterpret_cast<const float4*>(embed + c * VQ_DIM);
        float a0 = 0.0f, a1 = 0.0f, a2 = 0.0f, a3 = 0.0f;
#pragma unroll
        for (int j = 0; j < VQ_DIM / 4; ++j) {
            float4 v = ep[j];
            a0 = fmaf(xr[4 * j + 0], v.x, a0);
            a1 = fmaf(xr[4 * j + 1], v.y, a1);
            a2 = fmaf(xr[4 * j + 2], v.z, a2);
            a3 = fmaf(xr[4 * j + 3], v.w, a3);
        }
        float dot = (a0 + a1) + (a2 + a3);
        float score = fmaf(-2.0f, dot, e2s[c]);
        if (score < best) { best = score; bidx = c; }
    }

    // Gather embed[bidx] -> out row (embed is L2/L3 resident).
    const float4* bp = reinterpret_cast<const float4*>(embed + (size_t)bidx * VQ_DIM);
    float4* op = reinterpret_cast<float4*>(out + (size_t)row * VQ_DIM);
#pragma unroll
    for (int j = 0; j < VQ_DIM / 4; ++j) op[j] = bp[j];
}

extern "C" void kernel_launch(void* const* d_in, const int* in_sizes, int n_in,
                              void* d_out, int out_size, void* d_ws, size_t ws_size,
                              hipStream_t stream) {
    const float* x = (const float*)d_in[0];
    const float* embed = (const float*)d_in[1];
    float* out = (float*)d_out;
    dim3 grid(VQ_N / VQ_BLOCK);
    dim3 block(VQ_BLOCK);
    hipLaunchKernelGGL(vq_fp32_kernel, grid, block, 0, stream, x, embed, out);
}

// Round 2
// 226.527 us; speedup vs baseline: 2.7780x; 2.7780x over previous
//
#include <hip/hip_runtime.h>

// VQ: N=262144 rows, DIM=64, K=1024 codes.
// Stage 1 (MFMA bf16-split): S = ||e||^2 - 2 x.e via A = -2x (hi+lo bf16),
//   B = e (hi+lo bf16), acc init = ||e||^2. Track best/second-best packed keys.
// Stage 2 (exact fp32): re-solve rows whose margin < FLAG_EPS.
// np.argmin first-min tie-break preserved via (score,index)-ordered packed keys.

#define VQ_N 262144
#define VQ_DIM 64
#define VQ_K 1024
#define NCT (VQ_K / 16)          // 64 code-tiles of 16
#define FLAG_EPS 6.0e-3f

typedef short short8 __attribute__((ext_vector_type(8)));
typedef float f32x4 __attribute__((ext_vector_type(4)));

// ws layout (bytes):
#define WS_HI    0            // ebt_hi: ushort[1024*64] fragment-ordered (128 KB)
#define WS_LO    (128*1024)   // ebt_lo: ushort[1024*64]                  (128 KB)
#define WS_E2    (256*1024)   // e2: float[1024]                          (4 KB)
#define WS_FLAGS (260*1024)   // flags: u32[8192] bitmask over rows       (32 KB)
#define WS_NEEDED (292*1024)

static __device__ __forceinline__ unsigned short f2bf_rtne(float f) {
    unsigned u = __float_as_uint(f);
    unsigned r = u + 0x7FFFu + ((u >> 16) & 1u);
    return (unsigned short)(r >> 16);
}
static __device__ __forceinline__ float bf2f(unsigned short h) {
    return __uint_as_float(((unsigned)h) << 16);
}

// ---------------- prep: build B-fragments, e2, zero flags ----------------
// grid 32 x 256 = 8192 threads; thread t -> (ct = t>>7, kc = (t>>6)&1, l = t&63)
// ebt[(ct*2+kc)*64 + l][j] = bf16(embed[ct*16 + (l&15)][kc*32 + (l>>4)*8 + j])
__global__ void vq_prep(const float* __restrict__ embed, unsigned char* __restrict__ ws) {
    int t = blockIdx.x * 256 + threadIdx.x;  // 0..8191
    unsigned short* hi = (unsigned short*)(ws + WS_HI);
    unsigned short* lo = (unsigned short*)(ws + WS_LO);
    float* e2 = (float*)(ws + WS_E2);
    unsigned* flags = (unsigned*)(ws + WS_FLAGS);
    flags[t] = 0u;  // exactly 8192 words

    int ct = t >> 7;
    int kc = (t >> 6) & 1;
    int l = t & 63;
    int code = ct * 16 + (l & 15);
    int kb = kc * 32 + (l >> 4) * 8;
    const float* ep = embed + code * VQ_DIM + kb;
#pragma unroll
    for (int j = 0; j < 8; ++j) {
        float v = ep[j];
        unsigned short h = f2bf_rtne(v);
        hi[t * 8 + j] = h;
        lo[t * 8 + j] = f2bf_rtne(v - bf2f(h));
    }
    if (t < VQ_K) {
        const float* e = embed + t * VQ_DIM;
        float a0 = 0, a1 = 0, a2 = 0, a3 = 0;
#pragma unroll
        for (int j = 0; j < VQ_DIM; j += 4) {
            a0 = fmaf(e[j], e[j], a0);
            a1 = fmaf(e[j + 1], e[j + 1], a1);
            a2 = fmaf(e[j + 2], e[j + 2], a2);
            a3 = fmaf(e[j + 3], e[j + 3], a3);
        }
        e2[t] = (a0 + a1) + (a2 + a3);
    }
}

// ---------------- stage 1: MFMA scan, 64 rows/block (16/wave) ----------------
__global__ __launch_bounds__(256, 2)
void vq_stage1(const float* __restrict__ x, const float* __restrict__ embed,
               const unsigned char* __restrict__ wsro, unsigned char* __restrict__ ws,
               float* __restrict__ out) {
    __shared__ float e2s[VQ_K];
    const short8* bhp = (const short8*)(wsro + WS_HI);
    const short8* blp = (const short8*)(wsro + WS_LO);
    const float* e2g = (const float*)(wsro + WS_E2);
    unsigned* flags = (unsigned*)(ws + WS_FLAGS);

    for (int c = threadIdx.x; c < VQ_K; c += 256) e2s[c] = e2g[c];
    __syncthreads();

    const int lane = threadIdx.x & 63;
    const int wave = threadIdx.x >> 6;
    const int R0 = (blockIdx.x * 4 + wave) * 16;
    const int row = R0 + (lane & 15);
    const int kb = (lane >> 4) * 8;

    // A fragments: -2*x row, hi/lo bf16 split. A[row=lane&15][k=8*(lane>>4)+j]
    short8 ah0, al0, ah1, al1;
    {
        const float* xp = x + (size_t)row * VQ_DIM;
#pragma unroll
        for (int j = 0; j < 8; ++j) {
            float v = -2.0f * xp[kb + j];
            unsigned short h = f2bf_rtne(v);
            ah0[j] = (short)h;
            al0[j] = (short)f2bf_rtne(v - bf2f(h));
            float w = -2.0f * xp[32 + kb + j];
            unsigned short h2 = f2bf_rtne(w);
            ah1[j] = (short)h2;
            al1[j] = (short)f2bf_rtne(w - bf2f(h2));
        }
    }

    unsigned m1k[4], m2k[4];
#pragma unroll
    for (int r = 0; r < 4; ++r) { m1k[r] = 0xFFFFFFFFu; m2k[r] = 0xFFFFFFFFu; }

    for (int ct = 0; ct < NCT; ++ct) {
        float e2c = e2s[ct * 16 + (lane & 15)];
        short8 bh0 = bhp[(ct * 2 + 0) * 64 + lane];
        short8 bh1 = bhp[(ct * 2 + 1) * 64 + lane];
        short8 bl0 = blp[(ct * 2 + 0) * 64 + lane];
        short8 bl1 = blp[(ct * 2 + 1) * 64 + lane];

        f32x4 accm = {e2c, e2c, e2c, e2c};
        accm = __builtin_amdgcn_mfma_f32_16x16x32_bf16(ah0, bh0, accm, 0, 0, 0);
        accm = __builtin_amdgcn_mfma_f32_16x16x32_bf16(ah1, bh1, accm, 0, 0, 0);
        f32x4 accc = {0.f, 0.f, 0.f, 0.f};
        accc = __builtin_amdgcn_mfma_f32_16x16x32_bf16(al0, bh0, accc, 0, 0, 0);
        accc = __builtin_amdgcn_mfma_f32_16x16x32_bf16(al1, bh1, accc, 0, 0, 0);
        accc = __builtin_amdgcn_mfma_f32_16x16x32_bf16(ah0, bl0, accc, 0, 0, 0);
        accc = __builtin_amdgcn_mfma_f32_16x16x32_bf16(ah1, bl1, accc, 0, 0, 0);

#pragma unroll
        for (int r = 0; r < 4; ++r) {
            float s = accm[r] + accc[r];
            // order-preserving uint; pack ct in low 6 bits -> first-min tie-break
            unsigned b = __float_as_uint(s);
            unsigned u = b ^ (unsigned)(((int)b >> 31) | 0x80000000);
            unsigned key = (u & 0xFFFFFFC0u) | (unsigned)ct;
            unsigned mx = m1k[r] > key ? m1k[r] : key;
            unsigned mn = m1k[r] > key ? key : m1k[r];
            m2k[r] = m2k[r] < mx ? m2k[r] : mx;
            m1k[r] = mn;
        }
    }

    // cross-lane reduce over 16 lanes (same row group); res = code residue
    unsigned res[4];
#pragma unroll
    for (int r = 0; r < 4; ++r) res[r] = (unsigned)(lane & 15);
#pragma unroll
    for (int m = 1; m <= 8; m <<= 1) {
#pragma unroll
        for (int r = 0; r < 4; ++r) {
            unsigned ok = (unsigned)__shfl_xor((int)m1k[r], m);
            unsigned ore = (unsigned)__shfl_xor((int)res[r], m);
            unsigned ok2 = (unsigned)__shfl_xor((int)m2k[r], m);
            unsigned mx = m1k[r] > ok ? m1k[r] : ok;
            unsigned cand2 = ok2 < mx ? ok2 : mx;
            m2k[r] = m2k[r] < cand2 ? m2k[r] : cand2;
            bool take = (ok < m1k[r]) || (ok == m1k[r] && ore < res[r]);
            if (take) { m1k[r] = ok; res[r] = ore; }
        }
    }

    unsigned idx[4];
    float marg[4];
#pragma unroll
    for (int r = 0; r < 4; ++r) {
        idx[r] = ((m1k[r] & 63u) << 4) | res[r];
        unsigned u1 = m1k[r] & 0xFFFFFFC0u;
        unsigned u2 = m2k[r] & 0xFFFFFFC0u;
        float s1 = __uint_as_float((u1 & 0x80000000u) ? (u1 ^ 0x80000000u) : ~u1);
        float s2 = __uint_as_float((u2 & 0x80000000u) ? (u2 ^ 0x80000000u) : ~u2);
        marg[r] = s2 - s1;
    }

    if ((lane & 15) == 0) {
        int g = lane >> 4;
#pragma unroll
        for (int r = 0; r < 4; ++r) {
            if (marg[r] < FLAG_EPS) {
                int fr = R0 + g * 4 + r;
                atomicOr(&flags[fr >> 5], 1u << (fr & 31));
            }
        }
    }

    // fused gather: lane writes row R0+(lane&15); fetch that row's idx
    int g2 = (lane & 15) >> 2;
    int r2 = (lane & 15) & 3;
    int src = g2 << 4;
    unsigned i0 = (unsigned)__shfl((int)idx[0], src);
    unsigned i1 = (unsigned)__shfl((int)idx[1], src);
    unsigned i2 = (unsigned)__shfl((int)idx[2], src);
    unsigned i3 = (unsigned)__shfl((int)idx[3], src);
    unsigned my = (r2 == 0) ? i0 : (r2 == 1) ? i1 : (r2 == 2) ? i2 : i3;

    const float4* ef = (const float4*)embed;
    float4* of = (float4*)out;
    size_t obase = (size_t)(R0 + (lane & 15)) * (VQ_DIM / 4) + (lane >> 4) * 4;
    size_t ebase = (size_t)my * (VQ_DIM / 4) + (lane >> 4) * 4;
#pragma unroll
    for (int j = 0; j < 4; ++j) of[obase + j] = ef[ebase + j];
}

// ---------------- stage 2: exact fp32 re-solve of flagged rows ----------------
__global__ __launch_bounds__(256, 4)
void vq_stage2(const float* __restrict__ x, const float* __restrict__ embed,
               const unsigned char* __restrict__ ws, float* __restrict__ out) {
    const unsigned* flags = (const unsigned*)(ws + WS_FLAGS);
    const float* e2 = (const float*)(ws + WS_E2);
    int lane = threadIdx.x & 63;
    int wave = threadIdx.x >> 6;
    int w = blockIdx.x * 4 + wave;
    int rowbase = w * 64;
    unsigned fw = flags[(rowbase >> 5) + (lane >> 5)];
    int bit = (fw >> (lane & 31)) & 1;
    unsigned long long ball = __ballot(bit);
    while (ball) {
        int b = __ffsll(ball) - 1;
        ball &= ball - 1;
        int row = rowbase + b;
        const float* xr = x + (size_t)row * VQ_DIM;
        float best = __builtin_inff();
        int bi = VQ_K;
        for (int t = 0; t < VQ_K / 64; ++t) {
            int c = t * 64 + lane;
            const float* ep = embed + (size_t)c * VQ_DIM;
            float a0 = 0, a1 = 0, a2 = 0, a3 = 0;
#pragma unroll
            for (int j = 0; j < VQ_DIM; j += 4) {
                a0 = fmaf(xr[j], ep[j], a0);
                a1 = fmaf(xr[j + 1], ep[j + 1], a1);
                a2 = fmaf(xr[j + 2], ep[j + 2], a2);
                a3 = fmaf(xr[j + 3], ep[j + 3], a3);
            }
            float dot = (a0 + a1) + (a2 + a3);
            float s = fmaf(-2.0f, dot, e2[c]);
            if (s < best) { best = s; bi = c; }
        }
#pragma unroll
        for (int m = 1; m <= 32; m <<= 1) {
            float ob = __shfl_xor(best, m);
            int oi = __shfl_xor(bi, m);
            if (ob < best || (ob == best && oi < bi)) { best = ob; bi = oi; }
        }
        out[(size_t)row * VQ_DIM + lane] = embed[(size_t)bi * VQ_DIM + lane];
    }
}

// ---------------- fallback (round-1 fp32, used only if ws too small) ----------
__global__ __launch_bounds__(256, 4)
void vq_fallback(const float* __restrict__ x, const float* __restrict__ embed,
                 float* __restrict__ out) {
    __shared__ float e2s[VQ_K];
    const int tid = threadIdx.x;
    for (int c = tid; c < VQ_K; c += 256) {
        const float4* ep = (const float4*)(embed + c * VQ_DIM);
        float s = 0.0f;
#pragma unroll
        for (int j = 0; j < VQ_DIM / 4; ++j) {
            float4 v = ep[j];
            s = fmaf(v.x, v.x, s); s = fmaf(v.y, v.y, s);
            s = fmaf(v.z, v.z, s); s = fmaf(v.w, v.w, s);
        }
        e2s[c] = s;
    }
    __syncthreads();
    const int row = blockIdx.x * 256 + tid;
    float xr[VQ_DIM];
    const float4* xp = (const float4*)(x + (size_t)row * VQ_DIM);
#pragma unroll
    for (int j = 0; j < VQ_DIM / 4; ++j) {
        float4 v = xp[j];
        xr[4 * j] = v.x; xr[4 * j + 1] = v.y; xr[4 * j + 2] = v.z; xr[4 * j + 3] = v.w;
    }
    float best = __builtin_inff();
    int bidx = 0;
    for (int c = 0; c < VQ_K; ++c) {
        const float4* ep = (const float4*)(embed + c * VQ_DIM);
        float a0 = 0, a1 = 0, a2 = 0, a3 = 0;
#pragma unroll
        for (int j = 0; j < VQ_DIM / 4; ++j) {
            float4 v = ep[j];
            a0 = fmaf(xr[4 * j], v.x, a0);
            a1 = fmaf(xr[4 * j + 1], v.y, a1);
            a2 = fmaf(xr[4 * j + 2], v.z, a2);
            a3 = fmaf(xr[4 * j + 3], v.w, a3);
        }
        float score = fmaf(-2.0f, (a0 + a1) + (a2 + a3), e2s[c]);
        if (score < best) { best = score; bidx = c; }
    }
    const float4* bp = (const float4*)(embed + (size_t)bidx * VQ_DIM);
    float4* op = (float4*)(out + (size_t)row * VQ_DIM);
#pragma unroll
    for (int j = 0; j < VQ_DIM / 4; ++j) op[j] = bp[j];
}

extern "C" void kernel_launch(void* const* d_in, const int* in_sizes, int n_in,
                              void* d_out, int out_size, void* d_ws, size_t ws_size,
                              hipStream_t stream) {
    const float* x = (const float*)d_in[0];
    const float* embed = (const float*)d_in[1];
    float* out = (float*)d_out;
    if (ws_size < WS_NEEDED) {
        hipLaunchKernelGGL(vq_fallback, dim3(VQ_N / 256), dim3(256), 0, stream, x, embed, out);
        return;
    }
    unsigned char* ws = (unsigned char*)d_ws;
    hipLaunchKernelGGL(vq_prep, dim3(32), dim3(256), 0, stream, embed, ws);
    hipLaunchKernelGGL(vq_stage1, dim3(VQ_N / 64), dim3(256), 0, stream, x, embed, ws, ws, out);
    hipLaunchKernelGGL(vq_stage2, dim3(VQ_N / 256), dim3(256), 0, stream, x, embed, ws, out);
}